// Round 2
// baseline (11887.299 us; speedup 1.0000x reference)
//
#include <hip/hip_runtime.h>

// GCN: 4 layers, N=100000 nodes, E=1600000 edges, dims 256->128->64->16->40.
// proj = (h*norm_src)@W  [register-blocked 4x4 float4 GEMM]
// agg  = scatter_sum over edges (fp32 atomics)
// post = *norm_dst + bias, ReLU (except last)

__global__ void k_deg(const int* __restrict__ src, const int* __restrict__ dst,
                      float* __restrict__ degA, float* __restrict__ degB, int E) {
    int stride = gridDim.x * blockDim.x;
    for (int i = blockIdx.x * blockDim.x + threadIdx.x; i < E; i += stride) {
        atomicAdd(&degA[src[i]], 1.0f);
        atomicAdd(&degB[dst[i]], 1.0f);
    }
}

__global__ void k_norm(float* __restrict__ degA, float* __restrict__ degB, int N) {
    int stride = gridDim.x * blockDim.x;
    for (int i = blockIdx.x * blockDim.x + threadIdx.x; i < N; i += stride) {
        degA[i] = rsqrtf(fmaxf(degA[i], 1.0f));
        degB[i] = rsqrtf(fmaxf(degB[i], 1.0f));
    }
}

// out[n, j..j+3] = norm[n] * (in[n,:] @ W[:, j..j+3]), 4 rows per thread.
template<int DIN, int DOUT>
__global__ void __launch_bounds__(256) k_proj_t(
        const float* __restrict__ in, const float* __restrict__ norm,
        const float* __restrict__ W, float* __restrict__ out, int N) {
    constexpr int JG = DOUT / 4;   // float4 column groups
    constexpr int K4 = DIN / 4;
    int ngroups = (N + 3) >> 2;
    long total = (long)ngroups * JG;
    long t = blockIdx.x * 256L + threadIdx.x;
    if (t >= total) return;
    int rg = (int)(t / JG);
    int jg = (int)(t - (long)rg * JG);
    int j = jg * 4;
    int n0 = rg * 4;

    int n[4];
#pragma unroll
    for (int r = 0; r < 4; ++r) n[r] = (n0 + r < N) ? n0 + r : N - 1;

    const float4* rows[4];
#pragma unroll
    for (int r = 0; r < 4; ++r) rows[r] = (const float4*)(in + (long)n[r] * DIN);

    float4 acc[4];
#pragma unroll
    for (int r = 0; r < 4; ++r) acc[r] = make_float4(0.f, 0.f, 0.f, 0.f);

#pragma unroll
    for (int k4 = 0; k4 < K4; ++k4) {
        const float* wb = W + (4 * k4) * DOUT + j;
        float4 w0 = *(const float4*)(wb);
        float4 w1 = *(const float4*)(wb + DOUT);
        float4 w2 = *(const float4*)(wb + 2 * DOUT);
        float4 w3 = *(const float4*)(wb + 3 * DOUT);
#pragma unroll
        for (int r = 0; r < 4; ++r) {
            float4 rv = rows[r][k4];
            acc[r].x = fmaf(rv.x, w0.x, acc[r].x);
            acc[r].y = fmaf(rv.x, w0.y, acc[r].y);
            acc[r].z = fmaf(rv.x, w0.z, acc[r].z);
            acc[r].w = fmaf(rv.x, w0.w, acc[r].w);
            acc[r].x = fmaf(rv.y, w1.x, acc[r].x);
            acc[r].y = fmaf(rv.y, w1.y, acc[r].y);
            acc[r].z = fmaf(rv.y, w1.z, acc[r].z);
            acc[r].w = fmaf(rv.y, w1.w, acc[r].w);
            acc[r].x = fmaf(rv.z, w2.x, acc[r].x);
            acc[r].y = fmaf(rv.z, w2.y, acc[r].y);
            acc[r].z = fmaf(rv.z, w2.z, acc[r].z);
            acc[r].w = fmaf(rv.z, w2.w, acc[r].w);
            acc[r].x = fmaf(rv.w, w3.x, acc[r].x);
            acc[r].y = fmaf(rv.w, w3.y, acc[r].y);
            acc[r].z = fmaf(rv.w, w3.z, acc[r].z);
            acc[r].w = fmaf(rv.w, w3.w, acc[r].w);
        }
    }

#pragma unroll
    for (int r = 0; r < 4; ++r) {
        if (n0 + r < N) {
            float s = norm[n[r]];
            float4 o = make_float4(acc[r].x * s, acc[r].y * s, acc[r].z * s, acc[r].w * s);
            *(float4*)(out + (long)(n0 + r) * DOUT + j) = o;
        }
    }
}

// agg[dst[e], fg*4..+3] += proj[src[e], fg*4..+3]
template<int DOUT>
__global__ void __launch_bounds__(256) k_agg_t(
        const int* __restrict__ src, const int* __restrict__ dst,
        const float* __restrict__ proj, float* __restrict__ agg, int E) {
    constexpr int FG = DOUT / 4;
    long total = (long)E * FG;
    long i = blockIdx.x * 256L + threadIdx.x;
    if (i >= total) return;
    int e = (int)(i / FG);
    int fg = (int)(i - (long)e * FG);
    int s = src[e];
    int d = dst[e];
    float4 v = *(const float4*)(proj + (long)s * DOUT + fg * 4);
    float* p = agg + (long)d * DOUT + fg * 4;
    atomicAdd(p + 0, v.x);
    atomicAdd(p + 1, v.y);
    atomicAdd(p + 2, v.z);
    atomicAdd(p + 3, v.w);
}

// out[n, fg*4..+3] = act(agg*norm[n] + bias)
template<int DOUT, bool RELU>
__global__ void __launch_bounds__(256) k_post_t(
        const float* __restrict__ agg, const float* __restrict__ norm,
        const float* __restrict__ bias, float* __restrict__ out, int N) {
    constexpr int FG = DOUT / 4;
    long total = (long)N * FG;
    long i = blockIdx.x * 256L + threadIdx.x;
    if (i >= total) return;
    int n = (int)(i / FG);
    int fg = (int)(i - (long)n * FG);
    float s = norm[n];
    float4 v = *(const float4*)(agg + (long)n * DOUT + fg * 4);
    float4 b = *(const float4*)(bias + fg * 4);
    float4 o;
    o.x = fmaf(v.x, s, b.x);
    o.y = fmaf(v.y, s, b.y);
    o.z = fmaf(v.z, s, b.z);
    o.w = fmaf(v.w, s, b.w);
    if (RELU) {
        o.x = fmaxf(o.x, 0.f); o.y = fmaxf(o.y, 0.f);
        o.z = fmaxf(o.z, 0.f); o.w = fmaxf(o.w, 0.f);
    }
    *(float4*)(out + (long)n * DOUT + fg * 4) = o;
}

static inline int cdiv(long a, int b) { return (int)((a + b - 1) / b); }

template<int DIN, int DOUT, bool RELU>
static void run_layer(const float* in, float* proj_buf, float* agg_buf, float* dest,
                      const float* normS, const float* normD,
                      const float* W, const float* b,
                      const int* src, const int* dst, int N, int E, hipStream_t stream) {
    long tproj = ((N + 3) / 4) * (long)(DOUT / 4);
    k_proj_t<DIN, DOUT><<<cdiv(tproj, 256), 256, 0, stream>>>(in, normS, W, proj_buf, N);
    hipMemsetAsync(agg_buf, 0, (size_t)N * DOUT * sizeof(float), stream);
    long tagg = (long)E * (DOUT / 4);
    k_agg_t<DOUT><<<cdiv(tagg, 256), 256, 0, stream>>>(src, dst, proj_buf, agg_buf, E);
    long tpost = (long)N * (DOUT / 4);
    k_post_t<DOUT, RELU><<<cdiv(tpost, 256), 256, 0, stream>>>(agg_buf, normD, b, dest, N);
}

extern "C" void kernel_launch(void* const* d_in, const int* in_sizes, int n_in,
                              void* d_out, int out_size, void* d_ws, size_t ws_size,
                              hipStream_t stream) {
    const float* x   = (const float*)d_in[0];
    const int*   src = (const int*)d_in[1];
    const int*   dst = (const int*)d_in[2];
    const float* W1 = (const float*)d_in[3];  const float* b1 = (const float*)d_in[4];
    const float* W2 = (const float*)d_in[5];  const float* b2 = (const float*)d_in[6];
    const float* W3 = (const float*)d_in[7];  const float* b3 = (const float*)d_in[8];
    const float* W4 = (const float*)d_in[9];  const float* b4 = (const float*)d_in[10];

    const int N = in_sizes[0] / 256;
    const int E = in_sizes[1];

    float* ws    = (float*)d_ws;
    float* normS = ws;                        // [N]
    float* normD = ws + N;                    // [N]
    float* pa    = ws + 2 * (size_t)N;        // [N*128]
    float* pb    = pa + (size_t)N * 128;      // [N*128]

    hipMemsetAsync(normS, 0, 2 * (size_t)N * sizeof(float), stream);
    k_deg<<<2048, 256, 0, stream>>>(src, dst, normS, normD, E);
    k_norm<<<(N + 255) / 256, 256, 0, stream>>>(normS, normD, N);

    // layer 1: x -> pa(proj) -> pb(agg) -> pa(dest)
    run_layer<256, 128, true>(x, pa, pb, pa, normS, normD, W1, b1, src, dst, N, E, stream);
    // layer 2: pa -> pb -> pa... keep buffers distinct from input:
    run_layer<128, 64, true>(pa, pb, pa + (size_t)N * 64, pb, normS, normD, W2, b2, src, dst, N, E, stream);
    // pb holds h2 (dest). layer 3:
    run_layer<64, 16, true>(pb, pa, pa + (size_t)N * 16, pb, normS, normD, W3, b3, src, dst, N, E, stream);
    // pb holds h3. layer 4 -> d_out:
    run_layer<16, 40, false>(pb, pa, pa + (size_t)N * 40, (float*)d_out, normS, normD, W4, b4, src, dst, N, E, stream);
}

// Round 3
// 704.841 us; speedup vs baseline: 16.8652x; 16.8652x over previous
//
#include <hip/hip_runtime.h>

// GCN 4 layers: N=100000, E=1600000, dims 256->128->64->16->40.
//  proj  : (h * rsqrt(deg_out)) @ W    [LDS-staged W, R4 rows x 4 cols/thread]
//  agg   : CSR-by-dst gather (no atomics), fused *rsqrt(deg_in) + bias + ReLU
//  CSR built per call: int histogram -> deterministic 3-kernel scan -> fill.

// ---------------- degree histogram ----------------
__global__ void k_hist(const int* __restrict__ src, const int* __restrict__ dst,
                       int* __restrict__ degO, int* __restrict__ degI, int E) {
    int stride = gridDim.x * blockDim.x;
    for (int i = blockIdx.x * blockDim.x + threadIdx.x; i < E; i += stride) {
        atomicAdd(&degO[src[i]], 1);
        atomicAdd(&degI[dst[i]], 1);
    }
}

// ---------------- prefix scan (1024 elems / block) ----------------
__global__ void k_blocksum(const int* __restrict__ deg, int* __restrict__ bsum, int N) {
    __shared__ int sh[256];
    int base = blockIdx.x * 1024;
    int s = 0;
    for (int i = threadIdx.x; i < 1024; i += 256) {
        int idx = base + i;
        s += (idx < N) ? deg[idx] : 0;
    }
    sh[threadIdx.x] = s; __syncthreads();
    for (int off = 128; off > 0; off >>= 1) {
        if (threadIdx.x < off) sh[threadIdx.x] += sh[threadIdx.x + off];
        __syncthreads();
    }
    if (threadIdx.x == 0) bsum[blockIdx.x] = sh[0];
}

__global__ void k_scan_bsums(const int* __restrict__ bsum, int* __restrict__ boffs, int nb) {
    if (blockIdx.x == 0 && threadIdx.x == 0) {
        int run = 0;
        for (int i = 0; i < nb; ++i) { boffs[i] = run; run += bsum[i]; }
    }
}

__global__ void k_blockscan(const int* __restrict__ deg, const int* __restrict__ boffs,
                            int* __restrict__ rowptr, int N) {
    __shared__ int sh[256];
    int base = blockIdx.x * 1024;
    int i0 = base + threadIdx.x * 4;
    int v[4]; int tot = 0;
#pragma unroll
    for (int r = 0; r < 4; ++r) {
        int idx = i0 + r;
        v[r] = (idx < N) ? deg[idx] : 0;
        tot += v[r];
    }
    sh[threadIdx.x] = tot; __syncthreads();
    for (int off = 1; off < 256; off <<= 1) {
        int t = (threadIdx.x >= off) ? sh[threadIdx.x - off] : 0;
        __syncthreads();
        sh[threadIdx.x] += t;
        __syncthreads();
    }
    int run = sh[threadIdx.x] - tot + boffs[blockIdx.x];   // exclusive prefix
#pragma unroll
    for (int r = 0; r < 4; ++r) {
        int idx = i0 + r;
        if (idx < N) rowptr[idx] = run;
        run += v[r];
    }
}

__global__ void k_fill(const int* __restrict__ src, const int* __restrict__ dst,
                       const int* __restrict__ rowptr, int* __restrict__ cursor,
                       int* __restrict__ col, int E) {
    int stride = gridDim.x * blockDim.x;
    for (int i = blockIdx.x * blockDim.x + threadIdx.x; i < E; i += stride) {
        int d = dst[i];
        int pos = rowptr[d] + atomicAdd(&cursor[d], 1);
        col[pos] = src[i];
    }
}

// ---------------- projection GEMM (LDS-staged W) ----------------
// out[n, cg*4..+3] = rsqrt(max(degO[n],1)) * (in[n,:] @ W[:, cg*4..+3])
template<int DIN, int DOUT, int R4>
__global__ void __launch_bounds__(256) k_proj_lds(
        const float* __restrict__ in, const int* __restrict__ degO,
        const float* __restrict__ W, float* __restrict__ out, int N) {
    constexpr int CG  = DOUT / 4;                       // float4 col groups
    constexpr int RPP = 256 / CG;                       // rows per pass
    constexpr int RB  = RPP * R4;                       // rows per block
    constexpr int KT  = (DIN * DOUT <= 8192) ? DIN : (8192 / DOUT);
    constexpr int NKT = DIN / KT;
    __shared__ float4 wlds[KT * CG];                    // <= 32 KB

    int tid = threadIdx.x;
    int rp  = tid / CG;
    int cg  = tid - rp * CG;
    bool active = (rp < RPP);
    int n0 = blockIdx.x * RB;

    int nrow[R4];
    const float4* xr[R4];
#pragma unroll
    for (int r = 0; r < R4; ++r) {
        int n = n0 + rp + r * RPP;
        nrow[r] = n;
        int nc = n < N ? n : N - 1;
        xr[r] = (const float4*)(in + (long)nc * DIN);
    }
    float4 acc[R4];
#pragma unroll
    for (int r = 0; r < R4; ++r) acc[r] = make_float4(0.f, 0.f, 0.f, 0.f);

    for (int kt = 0; kt < NKT; ++kt) {
        const float4* wsrc = (const float4*)(W + (size_t)kt * KT * DOUT);
        for (int i = tid; i < KT * CG; i += 256) wlds[i] = wsrc[i];
        __syncthreads();
        if (active) {
#pragma unroll 2
            for (int k4 = 0; k4 < KT / 4; ++k4) {
                float4 w0 = wlds[(k4 * 4 + 0) * CG + cg];
                float4 w1 = wlds[(k4 * 4 + 1) * CG + cg];
                float4 w2 = wlds[(k4 * 4 + 2) * CG + cg];
                float4 w3 = wlds[(k4 * 4 + 3) * CG + cg];
#pragma unroll
                for (int r = 0; r < R4; ++r) {
                    float4 xv = xr[r][kt * (KT / 4) + k4];
                    acc[r].x = fmaf(xv.x, w0.x, acc[r].x);
                    acc[r].y = fmaf(xv.x, w0.y, acc[r].y);
                    acc[r].z = fmaf(xv.x, w0.z, acc[r].z);
                    acc[r].w = fmaf(xv.x, w0.w, acc[r].w);
                    acc[r].x = fmaf(xv.y, w1.x, acc[r].x);
                    acc[r].y = fmaf(xv.y, w1.y, acc[r].y);
                    acc[r].z = fmaf(xv.y, w1.z, acc[r].z);
                    acc[r].w = fmaf(xv.y, w1.w, acc[r].w);
                    acc[r].x = fmaf(xv.z, w2.x, acc[r].x);
                    acc[r].y = fmaf(xv.z, w2.y, acc[r].y);
                    acc[r].z = fmaf(xv.z, w2.z, acc[r].z);
                    acc[r].w = fmaf(xv.z, w2.w, acc[r].w);
                    acc[r].x = fmaf(xv.w, w3.x, acc[r].x);
                    acc[r].y = fmaf(xv.w, w3.y, acc[r].y);
                    acc[r].z = fmaf(xv.w, w3.z, acc[r].z);
                    acc[r].w = fmaf(xv.w, w3.w, acc[r].w);
                }
            }
        }
        __syncthreads();
    }
    if (active) {
#pragma unroll
        for (int r = 0; r < R4; ++r) {
            int n = nrow[r];
            if (n < N) {
                int d = degO[n];
                float nm = rsqrtf((float)(d > 1 ? d : 1));
                float4 o = make_float4(acc[r].x * nm, acc[r].y * nm,
                                       acc[r].z * nm, acc[r].w * nm);
                *(float4*)(out + (size_t)n * DOUT + cg * 4) = o;
            }
        }
    }
}

// ---------------- CSR gather + fused epilogue ----------------
template<int DOUT, bool RELU>
__global__ void __launch_bounds__(256) k_gather(
        const int* __restrict__ rowptr, const int* __restrict__ col,
        const int* __restrict__ degI, const float* __restrict__ proj,
        const float* __restrict__ bias, float* __restrict__ out, int N) {
    constexpr int CG = DOUT / 4;
    long t = blockIdx.x * 256L + threadIdx.x;
    long total = (long)N * CG;
    if (t >= total) return;
    int n  = (int)(t / CG);
    int cg = (int)(t - (long)n * CG);
    int beg = rowptr[n];
    int dg  = degI[n];
    float4 acc = make_float4(0.f, 0.f, 0.f, 0.f);
    for (int i = 0; i < dg; ++i) {
        int s = col[beg + i];
        float4 v = *(const float4*)(proj + (size_t)s * DOUT + cg * 4);
        acc.x += v.x; acc.y += v.y; acc.z += v.z; acc.w += v.w;
    }
    float nm = rsqrtf((float)(dg > 1 ? dg : 1));
    float4 b = *(const float4*)(bias + cg * 4);
    float4 o;
    o.x = fmaf(acc.x, nm, b.x);
    o.y = fmaf(acc.y, nm, b.y);
    o.z = fmaf(acc.z, nm, b.z);
    o.w = fmaf(acc.w, nm, b.w);
    if (RELU) {
        o.x = fmaxf(o.x, 0.f); o.y = fmaxf(o.y, 0.f);
        o.z = fmaxf(o.z, 0.f); o.w = fmaxf(o.w, 0.f);
    }
    *(float4*)(out + (size_t)n * DOUT + cg * 4) = o;
}

// ---------------- fallback atomic path (if ws too small for CSR) ----------------
template<int DOUT>
__global__ void __launch_bounds__(256) k_agg_t(
        const int* __restrict__ src, const int* __restrict__ dst,
        const float* __restrict__ proj, float* __restrict__ agg, int E) {
    constexpr int FG = DOUT / 4;
    long total = (long)E * FG;
    long i = blockIdx.x * 256L + threadIdx.x;
    if (i >= total) return;
    int e  = (int)(i / FG);
    int fg = (int)(i - (long)e * FG);
    float4 v = *(const float4*)(proj + (size_t)src[e] * DOUT + fg * 4);
    float* p = agg + (size_t)dst[e] * DOUT + fg * 4;
    atomicAdd(p + 0, v.x); atomicAdd(p + 1, v.y);
    atomicAdd(p + 2, v.z); atomicAdd(p + 3, v.w);
}

template<int DOUT, bool RELU>
__global__ void __launch_bounds__(256) k_post_t(
        const float* __restrict__ agg, const int* __restrict__ degI,
        const float* __restrict__ bias, float* __restrict__ out, int N) {
    constexpr int FG = DOUT / 4;
    long total = (long)N * FG;
    long i = blockIdx.x * 256L + threadIdx.x;
    if (i >= total) return;
    int n  = (int)(i / FG);
    int fg = (int)(i - (long)n * FG);
    int d = degI[n];
    float nm = rsqrtf((float)(d > 1 ? d : 1));
    float4 v = *(const float4*)(agg + (size_t)n * DOUT + fg * 4);
    float4 b = *(const float4*)(bias + fg * 4);
    float4 o;
    o.x = fmaf(v.x, nm, b.x); o.y = fmaf(v.y, nm, b.y);
    o.z = fmaf(v.z, nm, b.z); o.w = fmaf(v.w, nm, b.w);
    if (RELU) {
        o.x = fmaxf(o.x, 0.f); o.y = fmaxf(o.y, 0.f);
        o.z = fmaxf(o.z, 0.f); o.w = fmaxf(o.w, 0.f);
    }
    *(float4*)(out + (size_t)n * DOUT + fg * 4) = o;
}

static inline int cdiv(long a, int b) { return (int)((a + b - 1) / b); }

extern "C" void kernel_launch(void* const* d_in, const int* in_sizes, int n_in,
                              void* d_out, int out_size, void* d_ws, size_t ws_size,
                              hipStream_t stream) {
    const float* x   = (const float*)d_in[0];
    const int*   src = (const int*)d_in[1];
    const int*   dst = (const int*)d_in[2];
    const float* W1 = (const float*)d_in[3];  const float* b1 = (const float*)d_in[4];
    const float* W2 = (const float*)d_in[5];  const float* b2 = (const float*)d_in[6];
    const float* W3 = (const float*)d_in[7];  const float* b3 = (const float*)d_in[8];
    const float* W4 = (const float*)d_in[9];  const float* b4 = (const float*)d_in[10];

    const int N = in_sizes[0] / 256;
    const int E = in_sizes[1];

    size_t need_csr = ((size_t)3 * N + E + 2 * (size_t)N * 128) * sizeof(int);

    int* ws_i = (int*)d_ws;

    if (ws_size >= need_csr) {
        // ---- CSR path ----
        int* degO   = ws_i;                // [N]
        int* degI   = ws_i + N;            // [N]
        int* rowptr = ws_i + 2 * (size_t)N;// [N]
        int* col    = ws_i + 3 * (size_t)N;// [E]
        float* projb = (float*)(ws_i + 3 * (size_t)N + E);   // [N*128]
        float* hbuf  = projb + (size_t)N * 128;              // [N*128]
        int* cursor = (int*)projb;         // alias (used before proj)
        int* bsum   = (int*)hbuf;          // alias (used before layers)
        int* boffs  = bsum + 4096;

        int nb = (N + 1023) / 1024;

        hipMemsetAsync(degO, 0, 2 * (size_t)N * sizeof(int), stream);
        k_hist<<<2048, 256, 0, stream>>>(src, dst, degO, degI, E);
        k_blocksum<<<nb, 256, 0, stream>>>(degI, bsum, N);
        k_scan_bsums<<<1, 64, 0, stream>>>(bsum, boffs, nb);
        k_blockscan<<<nb, 256, 0, stream>>>(degI, boffs, rowptr, N);
        hipMemsetAsync(cursor, 0, (size_t)N * sizeof(int), stream);
        k_fill<<<2048, 256, 0, stream>>>(src, dst, rowptr, cursor, col, E);

        // layer 1: x -> projb -> hbuf
        k_proj_lds<256, 128, 8><<<cdiv(N, 64), 256, 0, stream>>>(x, degO, W1, projb, N);
        k_gather<128, true><<<cdiv((long)N * 32, 256), 256, 0, stream>>>(
            rowptr, col, degI, projb, b1, hbuf, N);
        // layer 2
        k_proj_lds<128, 64, 4><<<cdiv(N, 64), 256, 0, stream>>>(hbuf, degO, W2, projb, N);
        k_gather<64, true><<<cdiv((long)N * 16, 256), 256, 0, stream>>>(
            rowptr, col, degI, projb, b2, hbuf, N);
        // layer 3
        k_proj_lds<64, 16, 1><<<cdiv(N, 64), 256, 0, stream>>>(hbuf, degO, W3, projb, N);
        k_gather<16, true><<<cdiv((long)N * 4, 256), 256, 0, stream>>>(
            rowptr, col, degI, projb, b3, hbuf, N);
        // layer 4 -> d_out
        k_proj_lds<16, 40, 2><<<cdiv(N, 50), 256, 0, stream>>>(hbuf, degO, W4, projb, N);
        k_gather<40, false><<<cdiv((long)N * 10, 256), 256, 0, stream>>>(
            rowptr, col, degI, projb, b4, (float*)d_out, N);
    } else {
        // ---- fallback: atomic scatter path ----
        int* degO = ws_i;                  // [N]
        int* degI = ws_i + N;              // [N]
        float* projb = (float*)(ws_i + 2 * (size_t)N);  // [N*128]
        float* hbuf  = projb + (size_t)N * 128;         // [N*128]

        hipMemsetAsync(degO, 0, 2 * (size_t)N * sizeof(int), stream);
        k_hist<<<2048, 256, 0, stream>>>(src, dst, degO, degI, E);

        // layer 1
        k_proj_lds<256, 128, 8><<<cdiv(N, 64), 256, 0, stream>>>(x, degO, W1, projb, N);
        hipMemsetAsync(hbuf, 0, (size_t)N * 128 * sizeof(float), stream);
        k_agg_t<128><<<cdiv((long)E * 32, 256), 256, 0, stream>>>(src, dst, projb, hbuf, E);
        k_post_t<128, true><<<cdiv((long)N * 32, 256), 256, 0, stream>>>(hbuf, degI, b1, hbuf, N);
        // layer 2
        k_proj_lds<128, 64, 4><<<cdiv(N, 64), 256, 0, stream>>>(hbuf, degO, W2, projb, N);
        hipMemsetAsync(hbuf, 0, (size_t)N * 64 * sizeof(float), stream);
        k_agg_t<64><<<cdiv((long)E * 16, 256), 256, 0, stream>>>(src, dst, projb, hbuf, E);
        k_post_t<64, true><<<cdiv((long)N * 16, 256), 256, 0, stream>>>(hbuf, degI, b2, hbuf, N);
        // layer 3
        k_proj_lds<64, 16, 1><<<cdiv(N, 64), 256, 0, stream>>>(hbuf, degO, W3, projb, N);
        hipMemsetAsync(hbuf, 0, (size_t)N * 16 * sizeof(float), stream);
        k_agg_t<16><<<cdiv((long)E * 4, 256), 256, 0, stream>>>(src, dst, projb, hbuf, E);
        k_post_t<16, true><<<cdiv((long)N * 4, 256), 256, 0, stream>>>(hbuf, degI, b3, hbuf, N);
        // layer 4
        k_proj_lds<16, 40, 2><<<cdiv(N, 50), 256, 0, stream>>>(hbuf, degO, W4, projb, N);
        hipMemsetAsync(projb, 0, (size_t)N * 40 * sizeof(float), stream);
        // NOTE: reuse projb as agg target is wrong (it's the source) -> use hbuf+offset
        // safe: aggregate into hbuf region beyond layer-4 input? hbuf holds input (N*16 used).
        float* agg4 = hbuf + (size_t)N * 64;  // disjoint from hbuf[0..N*16) input region
        hipMemsetAsync(agg4, 0, (size_t)N * 40 * sizeof(float), stream);
        k_agg_t<40><<<cdiv((long)E * 10, 256), 256, 0, stream>>>(src, dst, projb, agg4, E);
        k_post_t<40, false><<<cdiv((long)N * 10, 256), 256, 0, stream>>>(agg4, degI, b4, (float*)d_out, N);
    }
}

// Round 4
// 652.241 us; speedup vs baseline: 18.2253x; 1.0806x over previous
//
#include <hip/hip_runtime.h>

// GCN 4 layers: N=100000, E=1600000, dims 256->128->64->16->40.
//  L1-L3: proj-first ((h*nS)@W, LDS-staged W, 16KB tiles) -> CSR gather (+nD+b+ReLU)
//  L4   : aggregate-first (din=16 < dout=40): t=h3*nS fused into L3 gather epilogue,
//         plain CSR gather of t, then fused GEMM (agg@W4)*nD + b4 -> out.
//  CSR built per call: int histogram -> deterministic scan -> cursor fill.

// ---------------- degree histogram ----------------
__global__ void k_hist(const int* __restrict__ src, const int* __restrict__ dst,
                       int* __restrict__ degO, int* __restrict__ degI, int E) {
    int stride = gridDim.x * blockDim.x;
    for (int i = blockIdx.x * blockDim.x + threadIdx.x; i < E; i += stride) {
        atomicAdd(&degO[src[i]], 1);
        atomicAdd(&degI[dst[i]], 1);
    }
}

// ---------------- prefix scan (1024 elems / block) ----------------
__global__ void k_blocksum(const int* __restrict__ deg, int* __restrict__ bsum, int N) {
    __shared__ int sh[256];
    int base = blockIdx.x * 1024;
    int s = 0;
    for (int i = threadIdx.x; i < 1024; i += 256) {
        int idx = base + i;
        s += (idx < N) ? deg[idx] : 0;
    }
    sh[threadIdx.x] = s; __syncthreads();
    for (int off = 128; off > 0; off >>= 1) {
        if (threadIdx.x < off) sh[threadIdx.x] += sh[threadIdx.x + off];
        __syncthreads();
    }
    if (threadIdx.x == 0) bsum[blockIdx.x] = sh[0];
}

__global__ void k_scan_bsums(const int* __restrict__ bsum, int* __restrict__ boffs, int nb) {
    if (blockIdx.x == 0 && threadIdx.x == 0) {
        int run = 0;
        for (int i = 0; i < nb; ++i) { boffs[i] = run; run += bsum[i]; }
    }
}

__global__ void k_blockscan(const int* __restrict__ deg, const int* __restrict__ boffs,
                            int* __restrict__ rowptr, int N) {
    __shared__ int sh[256];
    int base = blockIdx.x * 1024;
    int i0 = base + threadIdx.x * 4;
    int v[4]; int tot = 0;
#pragma unroll
    for (int r = 0; r < 4; ++r) {
        int idx = i0 + r;
        v[r] = (idx < N) ? deg[idx] : 0;
        tot += v[r];
    }
    sh[threadIdx.x] = tot; __syncthreads();
    for (int off = 1; off < 256; off <<= 1) {
        int t = (threadIdx.x >= off) ? sh[threadIdx.x - off] : 0;
        __syncthreads();
        sh[threadIdx.x] += t;
        __syncthreads();
    }
    int run = sh[threadIdx.x] - tot + boffs[blockIdx.x];   // exclusive prefix
#pragma unroll
    for (int r = 0; r < 4; ++r) {
        int idx = i0 + r;
        if (idx < N) rowptr[idx] = run;
        run += v[r];
    }
}

__global__ void k_fill(const int* __restrict__ src, const int* __restrict__ dst,
                       const int* __restrict__ rowptr, int* __restrict__ cursor,
                       int* __restrict__ col, int E) {
    int stride = gridDim.x * blockDim.x;
    for (int i = blockIdx.x * blockDim.x + threadIdx.x; i < E; i += stride) {
        int d = dst[i];
        int pos = rowptr[d] + atomicAdd(&cursor[d], 1);
        col[pos] = src[i];
    }
}

// ---------------- projection GEMM (LDS-staged W, 16KB tiles) ----------------
// EPI=0: out = acc * rsqrt(max(degO[n],1))                      (pre-norm, no bias)
// EPI=1: out = acc * rsqrt(max(degI[n],1)) + bias               (final layer)
template<int DIN, int DOUT, int R4, int KT, int EPI>
__global__ void __launch_bounds__(256) k_proj_lds(
        const float* __restrict__ in, const int* __restrict__ deg,
        const float* __restrict__ W, const float* __restrict__ bias,
        float* __restrict__ out, int N) {
    constexpr int CG  = DOUT / 4;          // float4 col groups
    constexpr int RPP = 256 / CG;          // rows per pass
    constexpr int RB  = RPP * R4;          // rows per block
    constexpr int NKT = DIN / KT;
    static_assert(DIN % KT == 0 && KT % 4 == 0, "tile");
    __shared__ float4 wlds[KT * CG];       // <= 16 KB

    int tid = threadIdx.x;
    int rp  = tid / CG;
    int cg  = tid - rp * CG;
    bool active = (rp < RPP);
    int n0 = blockIdx.x * RB;

    int nrow[R4];
    const float4* xr[R4];
#pragma unroll
    for (int r = 0; r < R4; ++r) {
        int n = n0 + rp + r * RPP;
        nrow[r] = n;
        int nc = n < N ? n : N - 1;
        xr[r] = (const float4*)(in + (size_t)nc * DIN);
    }
    float4 acc[R4];
#pragma unroll
    for (int r = 0; r < R4; ++r) acc[r] = make_float4(0.f, 0.f, 0.f, 0.f);

    for (int kt = 0; kt < NKT; ++kt) {
        const float4* wsrc = (const float4*)(W + (size_t)kt * KT * DOUT);
        for (int i = tid; i < KT * CG; i += 256) wlds[i] = wsrc[i];
        __syncthreads();
        if (active) {
#pragma unroll 2
            for (int k4 = 0; k4 < KT / 4; ++k4) {
                float4 w0 = wlds[(k4 * 4 + 0) * CG + cg];
                float4 w1 = wlds[(k4 * 4 + 1) * CG + cg];
                float4 w2 = wlds[(k4 * 4 + 2) * CG + cg];
                float4 w3 = wlds[(k4 * 4 + 3) * CG + cg];
#pragma unroll
                for (int r = 0; r < R4; ++r) {
                    float4 xv = xr[r][kt * (KT / 4) + k4];
                    acc[r].x = fmaf(xv.x, w0.x, acc[r].x);
                    acc[r].y = fmaf(xv.x, w0.y, acc[r].y);
                    acc[r].z = fmaf(xv.x, w0.z, acc[r].z);
                    acc[r].w = fmaf(xv.x, w0.w, acc[r].w);
                    acc[r].x = fmaf(xv.y, w1.x, acc[r].x);
                    acc[r].y = fmaf(xv.y, w1.y, acc[r].y);
                    acc[r].z = fmaf(xv.y, w1.z, acc[r].z);
                    acc[r].w = fmaf(xv.y, w1.w, acc[r].w);
                    acc[r].x = fmaf(xv.z, w2.x, acc[r].x);
                    acc[r].y = fmaf(xv.z, w2.y, acc[r].y);
                    acc[r].z = fmaf(xv.z, w2.z, acc[r].z);
                    acc[r].w = fmaf(xv.z, w2.w, acc[r].w);
                    acc[r].x = fmaf(xv.w, w3.x, acc[r].x);
                    acc[r].y = fmaf(xv.w, w3.y, acc[r].y);
                    acc[r].z = fmaf(xv.w, w3.z, acc[r].z);
                    acc[r].w = fmaf(xv.w, w3.w, acc[r].w);
                }
            }
        }
        __syncthreads();
    }
    if (active) {
#pragma unroll
        for (int r = 0; r < R4; ++r) {
            int n = nrow[r];
            if (n < N) {
                int d = deg[n];
                float nm = rsqrtf((float)(d > 1 ? d : 1));
                float4 o;
                if (EPI == 0) {
                    o = make_float4(acc[r].x * nm, acc[r].y * nm,
                                    acc[r].z * nm, acc[r].w * nm);
                } else {
                    float4 b = *(const float4*)(bias + cg * 4);
                    o.x = fmaf(acc[r].x, nm, b.x);
                    o.y = fmaf(acc[r].y, nm, b.y);
                    o.z = fmaf(acc[r].z, nm, b.z);
                    o.w = fmaf(acc[r].w, nm, b.w);
                }
                *(float4*)(out + (size_t)n * DOUT + cg * 4) = o;
            }
        }
    }
}

// ---------------- CSR gather + fused epilogue ----------------
// NORMBIAS: o = acc*rsqrt(degI)+bias  else o = acc (plain sum).
// RELU: relu(o).  SCALESRC: o *= rsqrt(max(degO,1))  (pre-scale for next layer).
template<int DOUT, bool RELU, bool NORMBIAS, bool SCALESRC>
__global__ void __launch_bounds__(256) k_gather(
        const int* __restrict__ rowptr, const int* __restrict__ col,
        const int* __restrict__ degI, const int* __restrict__ degO,
        const float* __restrict__ proj, const float* __restrict__ bias,
        float* __restrict__ out, int N) {
    constexpr int CG = DOUT / 4;
    long t = blockIdx.x * 256L + threadIdx.x;
    long total = (long)N * CG;
    if (t >= total) return;
    int n  = (int)(t / CG);
    int cg = (int)(t - (long)n * CG);
    int beg = rowptr[n];
    int dg  = degI[n];
    float4 a0 = make_float4(0.f, 0.f, 0.f, 0.f);
    float4 a1 = make_float4(0.f, 0.f, 0.f, 0.f);
    int i = 0;
    for (; i + 2 <= dg; i += 2) {
        int s0 = col[beg + i];
        int s1 = col[beg + i + 1];
        float4 v0 = *(const float4*)(proj + (size_t)s0 * DOUT + cg * 4);
        float4 v1 = *(const float4*)(proj + (size_t)s1 * DOUT + cg * 4);
        a0.x += v0.x; a0.y += v0.y; a0.z += v0.z; a0.w += v0.w;
        a1.x += v1.x; a1.y += v1.y; a1.z += v1.z; a1.w += v1.w;
    }
    if (i < dg) {
        int s0 = col[beg + i];
        float4 v0 = *(const float4*)(proj + (size_t)s0 * DOUT + cg * 4);
        a0.x += v0.x; a0.y += v0.y; a0.z += v0.z; a0.w += v0.w;
    }
    float4 o = make_float4(a0.x + a1.x, a0.y + a1.y, a0.z + a1.z, a0.w + a1.w);
    if (NORMBIAS) {
        float nm = rsqrtf((float)(dg > 1 ? dg : 1));
        float4 b = *(const float4*)(bias + cg * 4);
        o.x = fmaf(o.x, nm, b.x);
        o.y = fmaf(o.y, nm, b.y);
        o.z = fmaf(o.z, nm, b.z);
        o.w = fmaf(o.w, nm, b.w);
    }
    if (RELU) {
        o.x = fmaxf(o.x, 0.f); o.y = fmaxf(o.y, 0.f);
        o.z = fmaxf(o.z, 0.f); o.w = fmaxf(o.w, 0.f);
    }
    if (SCALESRC) {
        int dO = degO[n];
        float ns = rsqrtf((float)(dO > 1 ? dO : 1));
        o.x *= ns; o.y *= ns; o.z *= ns; o.w *= ns;
    }
    *(float4*)(out + (size_t)n * DOUT + cg * 4) = o;
}

static inline int cdiv(long a, int b) { return (int)((a + b - 1) / b); }

extern "C" void kernel_launch(void* const* d_in, const int* in_sizes, int n_in,
                              void* d_out, int out_size, void* d_ws, size_t ws_size,
                              hipStream_t stream) {
    const float* x   = (const float*)d_in[0];
    const int*   src = (const int*)d_in[1];
    const int*   dst = (const int*)d_in[2];
    const float* W1 = (const float*)d_in[3];  const float* b1 = (const float*)d_in[4];
    const float* W2 = (const float*)d_in[5];  const float* b2 = (const float*)d_in[6];
    const float* W3 = (const float*)d_in[7];  const float* b3 = (const float*)d_in[8];
    const float* W4 = (const float*)d_in[9];  const float* b4 = (const float*)d_in[10];

    const int N = in_sizes[0] / 256;
    const int E = in_sizes[1];

    int* ws_i = (int*)d_ws;
    int* degO   = ws_i;                 // [N]
    int* degI   = ws_i + N;             // [N]
    int* rowptr = ws_i + 2 * (size_t)N; // [N]
    int* col    = ws_i + 3 * (size_t)N; // [E]
    float* projb = (float*)(ws_i + 3 * (size_t)N + E);  // [N*128]
    float* hbuf  = projb + (size_t)N * 128;             // [N*128]
    int* cursor = (int*)projb;          // alias (dead before first proj)
    int* bsum   = (int*)hbuf;           // alias (dead before first gather write)
    int* boffs  = bsum + 4096;

    int nb = (N + 1023) / 1024;

    // ---- CSR build ----
    hipMemsetAsync(degO, 0, 2 * (size_t)N * sizeof(int), stream);
    k_hist<<<2048, 256, 0, stream>>>(src, dst, degO, degI, E);
    k_blocksum<<<nb, 256, 0, stream>>>(degI, bsum, N);
    k_scan_bsums<<<1, 64, 0, stream>>>(bsum, boffs, nb);
    k_blockscan<<<nb, 256, 0, stream>>>(degI, boffs, rowptr, N);
    hipMemsetAsync(cursor, 0, (size_t)N * sizeof(int), stream);
    k_fill<<<2048, 256, 0, stream>>>(src, dst, rowptr, cursor, col, E);

    // ---- layer 1: x -> projb -> hbuf ----  (CG=32, RPP=8, R4=8 -> RB=64; KT=32 -> 16KB LDS)
    k_proj_lds<256, 128, 8, 32, 0><<<cdiv(N, 64), 256, 0, stream>>>(
        x, degO, W1, nullptr, projb, N);
    k_gather<128, true, true, false><<<cdiv((long)N * 32, 256), 256, 0, stream>>>(
        rowptr, col, degI, degO, projb, b1, hbuf, N);

    // ---- layer 2: hbuf -> projb -> hbuf ----  (CG=16, RPP=16, R4=4 -> RB=64; KT=64 -> 16KB)
    k_proj_lds<128, 64, 4, 64, 0><<<cdiv(N, 64), 256, 0, stream>>>(
        hbuf, degO, W2, nullptr, projb, N);
    k_gather<64, true, true, false><<<cdiv((long)N * 16, 256), 256, 0, stream>>>(
        rowptr, col, degI, degO, projb, b2, hbuf, N);

    // ---- layer 3: hbuf -> projb -> hbuf(t4 = relu(...)*norm_src) ----
    //      (CG=4, RPP=64, R4=1 -> RB=64; KT=64 -> 4KB LDS)
    k_proj_lds<64, 16, 1, 64, 0><<<cdiv(N, 64), 256, 0, stream>>>(
        hbuf, degO, W3, nullptr, projb, N);
    k_gather<16, true, true, true><<<cdiv((long)N * 4, 256), 256, 0, stream>>>(
        rowptr, col, degI, degO, projb, b3, hbuf, N);

    // ---- layer 4 (aggregate-first): agg4 = A @ t4 -> projb; out = (agg4@W4)*nD + b4 ----
    k_gather<16, false, false, false><<<cdiv((long)N * 4, 256), 256, 0, stream>>>(
        rowptr, col, degI, degO, hbuf, nullptr, projb, N);
    //      (CG=10, RPP=25, R4=2 -> RB=50; KT=16 -> 2.5KB LDS; EPI=1: *rsqrt(degI)+bias)
    k_proj_lds<16, 40, 2, 16, 1><<<cdiv(N, 50), 256, 0, stream>>>(
        projb, degI, W4, b4, (float*)d_out, N);
}

// Round 5
// 599.955 us; speedup vs baseline: 19.8137x; 1.0872x over previous
//
#include <hip/hip_runtime.h>

// GCN 4 layers: N=100000, E=1600000, dims 256->128->64->16->40.
//  L1-L2: proj via global_load_lds-staged x+W tiles (LDS), then CSR gather.
//  L3   : old global-x proj (tiny), gather fuses relu+norm_src for L4.
//  L4   : aggregate-first: gather t, then fused GEMM (agg@W4)*nD + b4 -> out.
//  CSR built per call: histogram -> deterministic scan -> cursor fill.

__device__ __forceinline__ void gload_lds16(const float4* g, float4* l) {
    __builtin_amdgcn_global_load_lds(
        (const __attribute__((address_space(1))) void*)g,
        (__attribute__((address_space(3))) void*)l,
        16, 0, 0);
}

// ---------------- degree histogram ----------------
__global__ void k_hist(const int* __restrict__ src, const int* __restrict__ dst,
                       int* __restrict__ degO, int* __restrict__ degI, int E) {
    int stride = gridDim.x * blockDim.x;
    for (int i = blockIdx.x * blockDim.x + threadIdx.x; i < E; i += stride) {
        atomicAdd(&degO[src[i]], 1);
        atomicAdd(&degI[dst[i]], 1);
    }
}

// ---------------- prefix scan (1024 elems / block) ----------------
__global__ void k_blocksum(const int* __restrict__ deg, int* __restrict__ bsum, int N) {
    __shared__ int sh[256];
    int base = blockIdx.x * 1024;
    int s = 0;
    for (int i = threadIdx.x; i < 1024; i += 256) {
        int idx = base + i;
        s += (idx < N) ? deg[idx] : 0;
    }
    sh[threadIdx.x] = s; __syncthreads();
    for (int off = 128; off > 0; off >>= 1) {
        if (threadIdx.x < off) sh[threadIdx.x] += sh[threadIdx.x + off];
        __syncthreads();
    }
    if (threadIdx.x == 0) bsum[blockIdx.x] = sh[0];
}

__global__ void k_scan_bsums(const int* __restrict__ bsum, int* __restrict__ boffs, int nb) {
    if (blockIdx.x == 0 && threadIdx.x == 0) {
        int run = 0;
        for (int i = 0; i < nb; ++i) { boffs[i] = run; run += bsum[i]; }
    }
}

__global__ void k_blockscan(const int* __restrict__ deg, const int* __restrict__ boffs,
                            int* __restrict__ rowptr, int N) {
    __shared__ int sh[256];
    int base = blockIdx.x * 1024;
    int i0 = base + threadIdx.x * 4;
    int v[4]; int tot = 0;
#pragma unroll
    for (int r = 0; r < 4; ++r) {
        int idx = i0 + r;
        v[r] = (idx < N) ? deg[idx] : 0;
        tot += v[r];
    }
    sh[threadIdx.x] = tot; __syncthreads();
    for (int off = 1; off < 256; off <<= 1) {
        int t = (threadIdx.x >= off) ? sh[threadIdx.x - off] : 0;
        __syncthreads();
        sh[threadIdx.x] += t;
        __syncthreads();
    }
    int run = sh[threadIdx.x] - tot + boffs[blockIdx.x];   // exclusive prefix
#pragma unroll
    for (int r = 0; r < 4; ++r) {
        int idx = i0 + r;
        if (idx < N) rowptr[idx] = run;
        run += v[r];
    }
}

__global__ void k_fill(const int* __restrict__ src, const int* __restrict__ dst,
                       const int* __restrict__ rowptr, int* __restrict__ cursor,
                       int* __restrict__ col, int E) {
    int stride = gridDim.x * blockDim.x;
    for (int i = blockIdx.x * blockDim.x + threadIdx.x; i < E; i += stride) {
        int d = dst[i];
        int pos = rowptr[d] + atomicAdd(&cursor[d], 1);
        col[pos] = src[i];
    }
}

// ---------------- proj GEMM: global_load_lds staged x and W ----------------
// out[n, cg*4..+3] = rsqrt(max(deg[n],1)) * (in[n,:] @ W[:, cg*4..+3])  (EPI=0)
// EPI=1: *rsqrt(deg)+bias (final layer form, unused here for L1/L2)
template<int DIN, int DOUT, int RB, int KT, int EPI>
__global__ void __launch_bounds__(256) k_proj_gl(
        const float* __restrict__ in, const int* __restrict__ deg,
        const float* __restrict__ W, const float* __restrict__ bias,
        float* __restrict__ out, int N) {
    constexpr int CG  = DOUT / 4;           // float4 col groups
    constexpr int RPP = 256 / CG;           // rows per pass
    constexpr int R4  = RB / RPP;           // rows per thread
    constexpr int K4T = KT / 4;             // float4 per row per tile (must be pow2)
    constexpr int NKT = DIN / KT;
    constexpr int XTILE = RB * K4T;         // float4 count
    constexpr int WTILE = KT * CG;
    static_assert(RPP * CG == 256, "full block");
    static_assert((K4T & (K4T - 1)) == 0, "pow2 swizzle");
    static_assert(XTILE % 256 == 0 && WTILE % 256 == 0, "stage granularity");
    __shared__ float4 wlds[WTILE];
    __shared__ float4 xlds[XTILE];

    int tid  = threadIdx.x;
    int wave = tid >> 6;
    int lane = tid & 63;
    int rp   = tid / CG;
    int cg   = tid - rp * CG;
    int n0   = blockIdx.x * RB;

    float4 acc[R4];
#pragma unroll
    for (int r = 0; r < R4; ++r) acc[r] = make_float4(0.f, 0.f, 0.f, 0.f);

    for (int kt = 0; kt < NKT; ++kt) {
        // ---- stage W tile (contiguous) ----
        const float4* wsrc = (const float4*)(W + (size_t)kt * KT * DOUT);
#pragma unroll
        for (int j = 0; j < WTILE / 256; ++j) {
            int base = j * 256 + wave * 64;
            gload_lds16(wsrc + base + lane, &wlds[base]);
        }
        // ---- stage x tile (source pre-swizzled so reads are bank-spread) ----
#pragma unroll
        for (int j = 0; j < XTILE / 256; ++j) {
            int base = j * 256 + wave * 64;
            int fi   = base + lane;
            int row  = fi / K4T;
            int k4   = fi - row * K4T;
            int k4s  = k4 ^ (row & (K4T - 1));
            int grow = n0 + row; if (grow >= N) grow = N - 1;
            const float4* gsrc = (const float4*)(in + (size_t)grow * DIN) + kt * K4T + k4s;
            gload_lds16(gsrc, &xlds[base]);
        }
        __syncthreads();
        // ---- compute ----
#pragma unroll 2
        for (int k4 = 0; k4 < K4T; ++k4) {
            float4 w0 = wlds[(k4 * 4 + 0) * CG + cg];
            float4 w1 = wlds[(k4 * 4 + 1) * CG + cg];
            float4 w2 = wlds[(k4 * 4 + 2) * CG + cg];
            float4 w3 = wlds[(k4 * 4 + 3) * CG + cg];
#pragma unroll
            for (int r = 0; r < R4; ++r) {
                int row = rp + r * RPP;
                float4 xv = xlds[row * K4T + (k4 ^ (row & (K4T - 1)))];
                acc[r].x = fmaf(xv.x, w0.x, acc[r].x);
                acc[r].y = fmaf(xv.x, w0.y, acc[r].y);
                acc[r].z = fmaf(xv.x, w0.z, acc[r].z);
                acc[r].w = fmaf(xv.x, w0.w, acc[r].w);
                acc[r].x = fmaf(xv.y, w1.x, acc[r].x);
                acc[r].y = fmaf(xv.y, w1.y, acc[r].y);
                acc[r].z = fmaf(xv.y, w1.z, acc[r].z);
                acc[r].w = fmaf(xv.y, w1.w, acc[r].w);
                acc[r].x = fmaf(xv.z, w2.x, acc[r].x);
                acc[r].y = fmaf(xv.z, w2.y, acc[r].y);
                acc[r].z = fmaf(xv.z, w2.z, acc[r].z);
                acc[r].w = fmaf(xv.z, w2.w, acc[r].w);
                acc[r].x = fmaf(xv.w, w3.x, acc[r].x);
                acc[r].y = fmaf(xv.w, w3.y, acc[r].y);
                acc[r].z = fmaf(xv.w, w3.z, acc[r].z);
                acc[r].w = fmaf(xv.w, w3.w, acc[r].w);
            }
        }
        __syncthreads();
    }
#pragma unroll
    for (int r = 0; r < R4; ++r) {
        int n = n0 + rp + r * RPP;
        if (n < N) {
            int d = deg[n];
            float nm = rsqrtf((float)(d > 1 ? d : 1));
            float4 o;
            if (EPI == 0) {
                o = make_float4(acc[r].x * nm, acc[r].y * nm,
                                acc[r].z * nm, acc[r].w * nm);
            } else {
                float4 b = *(const float4*)(bias + cg * 4);
                o.x = fmaf(acc[r].x, nm, b.x);
                o.y = fmaf(acc[r].y, nm, b.y);
                o.z = fmaf(acc[r].z, nm, b.z);
                o.w = fmaf(acc[r].w, nm, b.w);
            }
            *(float4*)(out + (size_t)n * DOUT + cg * 4) = o;
        }
    }
}

// ---------------- proj GEMM (old global-x form, for small layers 3/4) ----------------
template<int DIN, int DOUT, int R4, int KT, int EPI>
__global__ void __launch_bounds__(256) k_proj_lds(
        const float* __restrict__ in, const int* __restrict__ deg,
        const float* __restrict__ W, const float* __restrict__ bias,
        float* __restrict__ out, int N) {
    constexpr int CG  = DOUT / 4;
    constexpr int RPP = 256 / CG;
    constexpr int RB  = RPP * R4;
    constexpr int NKT = DIN / KT;
    static_assert(DIN % KT == 0 && KT % 4 == 0, "tile");
    __shared__ float4 wlds[KT * CG];

    int tid = threadIdx.x;
    int rp  = tid / CG;
    int cg  = tid - rp * CG;
    bool active = (rp < RPP);
    int n0 = blockIdx.x * RB;

    int nrow[R4];
    const float4* xr[R4];
#pragma unroll
    for (int r = 0; r < R4; ++r) {
        int n = n0 + rp + r * RPP;
        nrow[r] = n;
        int nc = n < N ? n : N - 1;
        xr[r] = (const float4*)(in + (size_t)nc * DIN);
    }
    float4 acc[R4];
#pragma unroll
    for (int r = 0; r < R4; ++r) acc[r] = make_float4(0.f, 0.f, 0.f, 0.f);

    for (int kt = 0; kt < NKT; ++kt) {
        const float4* wsrc = (const float4*)(W + (size_t)kt * KT * DOUT);
        for (int i = tid; i < KT * CG; i += 256) wlds[i] = wsrc[i];
        __syncthreads();
        if (active) {
#pragma unroll 2
            for (int k4 = 0; k4 < KT / 4; ++k4) {
                float4 w0 = wlds[(k4 * 4 + 0) * CG + cg];
                float4 w1 = wlds[(k4 * 4 + 1) * CG + cg];
                float4 w2 = wlds[(k4 * 4 + 2) * CG + cg];
                float4 w3 = wlds[(k4 * 4 + 3) * CG + cg];
#pragma unroll
                for (int r = 0; r < R4; ++r) {
                    float4 xv = xr[r][kt * (KT / 4) + k4];
                    acc[r].x = fmaf(xv.x, w0.x, acc[r].x);
                    acc[r].y = fmaf(xv.x, w0.y, acc[r].y);
                    acc[r].z = fmaf(xv.x, w0.z, acc[r].z);
                    acc[r].w = fmaf(xv.x, w0.w, acc[r].w);
                    acc[r].x = fmaf(xv.y, w1.x, acc[r].x);
                    acc[r].y = fmaf(xv.y, w1.y, acc[r].y);
                    acc[r].z = fmaf(xv.y, w1.z, acc[r].z);
                    acc[r].w = fmaf(xv.y, w1.w, acc[r].w);
                    acc[r].x = fmaf(xv.z, w2.x, acc[r].x);
                    acc[r].y = fmaf(xv.z, w2.y, acc[r].y);
                    acc[r].z = fmaf(xv.z, w2.z, acc[r].z);
                    acc[r].w = fmaf(xv.z, w2.w, acc[r].w);
                    acc[r].x = fmaf(xv.w, w3.x, acc[r].x);
                    acc[r].y = fmaf(xv.w, w3.y, acc[r].y);
                    acc[r].z = fmaf(xv.w, w3.z, acc[r].z);
                    acc[r].w = fmaf(xv.w, w3.w, acc[r].w);
                }
            }
        }
        __syncthreads();
    }
    if (active) {
#pragma unroll
        for (int r = 0; r < R4; ++r) {
            int n = nrow[r];
            if (n < N) {
                int d = deg[n];
                float nm = rsqrtf((float)(d > 1 ? d : 1));
                float4 o;
                if (EPI == 0) {
                    o = make_float4(acc[r].x * nm, acc[r].y * nm,
                                    acc[r].z * nm, acc[r].w * nm);
                } else {
                    float4 b = *(const float4*)(bias + cg * 4);
                    o.x = fmaf(acc[r].x, nm, b.x);
                    o.y = fmaf(acc[r].y, nm, b.y);
                    o.z = fmaf(acc[r].z, nm, b.z);
                    o.w = fmaf(acc[r].w, nm, b.w);
                }
                *(float4*)(out + (size_t)n * DOUT + cg * 4) = o;
            }
        }
    }
}

// ---------------- CSR gather + fused epilogue ----------------
template<int DOUT, bool RELU, bool NORMBIAS, bool SCALESRC>
__global__ void __launch_bounds__(256) k_gather(
        const int* __restrict__ rowptr, const int* __restrict__ col,
        const int* __restrict__ degI, const int* __restrict__ degO,
        const float* __restrict__ proj, const float* __restrict__ bias,
        float* __restrict__ out, int N) {
    constexpr int CG = DOUT / 4;
    long t = blockIdx.x * 256L + threadIdx.x;
    long total = (long)N * CG;
    if (t >= total) return;
    int n  = (int)(t / CG);
    int cg = (int)(t - (long)n * CG);
    int beg = rowptr[n];
    int dg  = degI[n];
    float4 a0 = make_float4(0.f, 0.f, 0.f, 0.f);
    float4 a1 = make_float4(0.f, 0.f, 0.f, 0.f);
    float4 a2 = make_float4(0.f, 0.f, 0.f, 0.f);
    float4 a3 = make_float4(0.f, 0.f, 0.f, 0.f);
    int i = 0;
    for (; i + 4 <= dg; i += 4) {
        int s0 = col[beg + i];
        int s1 = col[beg + i + 1];
        int s2 = col[beg + i + 2];
        int s3 = col[beg + i + 3];
        float4 v0 = *(const float4*)(proj + (size_t)s0 * DOUT + cg * 4);
        float4 v1 = *(const float4*)(proj + (size_t)s1 * DOUT + cg * 4);
        float4 v2 = *(const float4*)(proj + (size_t)s2 * DOUT + cg * 4);
        float4 v3 = *(const float4*)(proj + (size_t)s3 * DOUT + cg * 4);
        a0.x += v0.x; a0.y += v0.y; a0.z += v0.z; a0.w += v0.w;
        a1.x += v1.x; a1.y += v1.y; a1.z += v1.z; a1.w += v1.w;
        a2.x += v2.x; a2.y += v2.y; a2.z += v2.z; a2.w += v2.w;
        a3.x += v3.x; a3.y += v3.y; a3.z += v3.z; a3.w += v3.w;
    }
    for (; i < dg; ++i) {
        int s0 = col[beg + i];
        float4 v0 = *(const float4*)(proj + (size_t)s0 * DOUT + cg * 4);
        a0.x += v0.x; a0.y += v0.y; a0.z += v0.z; a0.w += v0.w;
    }
    float4 o = make_float4(a0.x + a1.x + a2.x + a3.x,
                           a0.y + a1.y + a2.y + a3.y,
                           a0.z + a1.z + a2.z + a3.z,
                           a0.w + a1.w + a2.w + a3.w);
    if (NORMBIAS) {
        float nm = rsqrtf((float)(dg > 1 ? dg : 1));
        float4 b = *(const float4*)(bias + cg * 4);
        o.x = fmaf(o.x, nm, b.x);
        o.y = fmaf(o.y, nm, b.y);
        o.z = fmaf(o.z, nm, b.z);
        o.w = fmaf(o.w, nm, b.w);
    }
    if (RELU) {
        o.x = fmaxf(o.x, 0.f); o.y = fmaxf(o.y, 0.f);
        o.z = fmaxf(o.z, 0.f); o.w = fmaxf(o.w, 0.f);
    }
    if (SCALESRC) {
        int dO = degO[n];
        float ns = rsqrtf((float)(dO > 1 ? dO : 1));
        o.x *= ns; o.y *= ns; o.z *= ns; o.w *= ns;
    }
    *(float4*)(out + (size_t)n * DOUT + cg * 4) = o;
}

static inline int cdiv(long a, int b) { return (int)((a + b - 1) / b); }

extern "C" void kernel_launch(void* const* d_in, const int* in_sizes, int n_in,
                              void* d_out, int out_size, void* d_ws, size_t ws_size,
                              hipStream_t stream) {
    const float* x   = (const float*)d_in[0];
    const int*   src = (const int*)d_in[1];
    const int*   dst = (const int*)d_in[2];
    const float* W1 = (const float*)d_in[3];  const float* b1 = (const float*)d_in[4];
    const float* W2 = (const float*)d_in[5];  const float* b2 = (const float*)d_in[6];
    const float* W3 = (const float*)d_in[7];  const float* b3 = (const float*)d_in[8];
    const float* W4 = (const float*)d_in[9];  const float* b4 = (const float*)d_in[10];

    const int N = in_sizes[0] / 256;
    const int E = in_sizes[1];

    int* ws_i = (int*)d_ws;
    int* degO   = ws_i;                 // [N]
    int* degI   = ws_i + N;             // [N]
    int* rowptr = ws_i + 2 * (size_t)N; // [N]
    int* col    = ws_i + 3 * (size_t)N; // [E]
    float* projb = (float*)(ws_i + 3 * (size_t)N + E);  // [N*128]
    float* hbuf  = projb + (size_t)N * 128;             // [N*128]
    int* cursor = (int*)projb;          // alias (dead before first proj)
    int* bsum   = (int*)hbuf;           // alias (dead before first gather write)
    int* boffs  = bsum + 4096;

    int nb = (N + 1023) / 1024;

    // ---- CSR build ----
    hipMemsetAsync(degO, 0, 2 * (size_t)N * sizeof(int), stream);
    k_hist<<<2048, 256, 0, stream>>>(src, dst, degO, degI, E);
    k_blocksum<<<nb, 256, 0, stream>>>(degI, bsum, N);
    k_scan_bsums<<<1, 64, 0, stream>>>(bsum, boffs, nb);
    k_blockscan<<<nb, 256, 0, stream>>>(degI, boffs, rowptr, N);
    hipMemsetAsync(cursor, 0, (size_t)N * sizeof(int), stream);
    k_fill<<<2048, 256, 0, stream>>>(src, dst, rowptr, cursor, col, E);

    // ---- layer 1: x -> projb -> hbuf ----  (RB=64, KT=32: W 16KB + x 8KB LDS)
    k_proj_gl<256, 128, 64, 32, 0><<<cdiv(N, 64), 256, 0, stream>>>(
        x, degO, W1, nullptr, projb, N);
    k_gather<128, true, true, false><<<cdiv((long)N * 32, 256), 256, 0, stream>>>(
        rowptr, col, degI, degO, projb, b1, hbuf, N);

    // ---- layer 2: hbuf -> projb -> hbuf ----  (RB=64, KT=32: W 8KB + x 8KB)
    k_proj_gl<128, 64, 64, 32, 0><<<cdiv(N, 64), 256, 0, stream>>>(
        hbuf, degO, W2, nullptr, projb, N);
    k_gather<64, true, true, false><<<cdiv((long)N * 16, 256), 256, 0, stream>>>(
        rowptr, col, degI, degO, projb, b2, hbuf, N);

    // ---- layer 3: hbuf -> projb -> hbuf(t4 = relu(...)*norm_src) ----
    k_proj_lds<64, 16, 1, 64, 0><<<cdiv(N, 64), 256, 0, stream>>>(
        hbuf, degO, W3, nullptr, projb, N);
    k_gather<16, true, true, true><<<cdiv((long)N * 4, 256), 256, 0, stream>>>(
        rowptr, col, degI, degO, projb, b3, hbuf, N);

    // ---- layer 4 (aggregate-first): agg4 = A @ t4 -> projb; out = (agg4@W4)*nD + b4 ----
    k_gather<16, false, false, false><<<cdiv((long)N * 4, 256), 256, 0, stream>>>(
        rowptr, col, degI, degO, hbuf, nullptr, projb, N);
    k_proj_lds<16, 40, 2, 16, 1><<<cdiv(N, 50), 256, 0, stream>>>(
        projb, degI, W4, b4, (float*)d_out, N);
}

// Round 7
// 504.845 us; speedup vs baseline: 23.5464x; 1.1884x over previous
//
#include <hip/hip_runtime.h>

// GCN 4 layers: N=100000, E=1600000, dims 256->128->64->16->40.
//  k_comb : blocks 3:2 split -> {proj1 P1=x@W1 (bf16, un-normalized)} || {degree histogram}
//  CSR    : scan (k_blockscan dual-stores rowptr AND cursor; NO memcpy node) -> fill
//  L1 agg : bf16 gather with per-edge nS[s] FMA, fused nD+b1+ReLU
//  L2     : proj (global_load_lds staged) -> fp32 gather
//  L3     : small proj -> gather (fused relu+nD+b3, then *nS for L4)
//  L4     : aggregate-first: plain gather t, fused GEMM (agg@W4)*nD+b4 -> out

typedef unsigned short ushort_t;

__device__ __forceinline__ void gload_lds16(const float4* g, float4* l) {
    __builtin_amdgcn_global_load_lds(
        (const __attribute__((address_space(1))) void*)g,
        (__attribute__((address_space(3))) void*)l, 16, 0, 0);
}

__device__ __forceinline__ ushort_t f2bf(float f) {
    unsigned u = __float_as_uint(f);
    u += 0x7FFFu + ((u >> 16) & 1u);          // RNE
    return (ushort_t)(u >> 16);
}
#define BFLO(u) __uint_as_float((u) << 16)
#define BFHI(u) __uint_as_float((u) & 0xffff0000u)

// ---------------- shared proj GEMM body (global_load_lds staged x and W) ------
template<int DIN, int DOUT, int RB, int KT, typename EPI>
__device__ __forceinline__ void proj_body(
        const float* __restrict__ in, const float* __restrict__ W,
        int N, int n0, float4* __restrict__ wlds, float4* __restrict__ xlds,
        EPI&& epi) {
    constexpr int CG  = DOUT / 4;
    constexpr int RPP = 256 / CG;
    constexpr int R4  = RB / RPP;
    constexpr int K4T = KT / 4;
    constexpr int NKT = DIN / KT;
    constexpr int XTILE = RB * K4T;
    constexpr int WTILE = KT * CG;
    static_assert(RPP * CG == 256, "full block");
    static_assert((K4T & (K4T - 1)) == 0, "pow2 swizzle");
    static_assert(XTILE % 256 == 0 && WTILE % 256 == 0, "stage granularity");

    const int tid  = threadIdx.x;
    const int wave = tid >> 6;
    const int lane = tid & 63;
    const int rp   = tid / CG;
    const int cg   = tid - rp * CG;

    float4 acc[R4];
#pragma unroll
    for (int r = 0; r < R4; ++r) acc[r] = make_float4(0.f, 0.f, 0.f, 0.f);

    for (int kt = 0; kt < NKT; ++kt) {
        const float4* wsrc = (const float4*)(W + (size_t)kt * KT * DOUT);
#pragma unroll
        for (int j = 0; j < WTILE / 256; ++j) {
            int base = j * 256 + wave * 64;
            gload_lds16(wsrc + base + lane, &wlds[base]);
        }
#pragma unroll
        for (int j = 0; j < XTILE / 256; ++j) {
            int base = j * 256 + wave * 64;
            int fi   = base + lane;
            int row  = fi / K4T;
            int k4   = fi - row * K4T;
            int k4s  = k4 ^ (row & (K4T - 1));
            int grow = n0 + row; if (grow >= N) grow = N - 1;
            const float4* gsrc = (const float4*)(in + (size_t)grow * DIN) + kt * K4T + k4s;
            gload_lds16(gsrc, &xlds[base]);
        }
        __syncthreads();
#pragma unroll 2
        for (int k4 = 0; k4 < K4T; ++k4) {
            float4 w0 = wlds[(k4 * 4 + 0) * CG + cg];
            float4 w1 = wlds[(k4 * 4 + 1) * CG + cg];
            float4 w2 = wlds[(k4 * 4 + 2) * CG + cg];
            float4 w3 = wlds[(k4 * 4 + 3) * CG + cg];
#pragma unroll
            for (int r = 0; r < R4; ++r) {
                int row = rp + r * RPP;
                float4 xv = xlds[row * K4T + (k4 ^ (row & (K4T - 1)))];
                acc[r].x = fmaf(xv.x, w0.x, acc[r].x);
                acc[r].y = fmaf(xv.x, w0.y, acc[r].y);
                acc[r].z = fmaf(xv.x, w0.z, acc[r].z);
                acc[r].w = fmaf(xv.x, w0.w, acc[r].w);
                acc[r].x = fmaf(xv.y, w1.x, acc[r].x);
                acc[r].y = fmaf(xv.y, w1.y, acc[r].y);
                acc[r].z = fmaf(xv.y, w1.z, acc[r].z);
                acc[r].w = fmaf(xv.y, w1.w, acc[r].w);
                acc[r].x = fmaf(xv.z, w2.x, acc[r].x);
                acc[r].y = fmaf(xv.z, w2.y, acc[r].y);
                acc[r].z = fmaf(xv.z, w2.z, acc[r].z);
                acc[r].w = fmaf(xv.z, w2.w, acc[r].w);
                acc[r].x = fmaf(xv.w, w3.x, acc[r].x);
                acc[r].y = fmaf(xv.w, w3.y, acc[r].y);
                acc[r].z = fmaf(xv.w, w3.z, acc[r].z);
                acc[r].w = fmaf(xv.w, w3.w, acc[r].w);
            }
        }
        __syncthreads();
    }
    epi(acc, rp, cg);
}

// ---------------- combined: proj1 (bf16, un-normalized) || histogram ----------
template<int DIN, int DOUT, int RB, int KT>
__global__ void __launch_bounds__(256) k_comb(
        const float* __restrict__ x, const float* __restrict__ W,
        ushort_t* __restrict__ outbf, int N,
        const int* __restrict__ src, const int* __restrict__ dst,
        int* __restrict__ degO, int* __restrict__ degI, int E, int PB, int HTH) {
    constexpr int CG  = DOUT / 4;
    constexpr int RPP = 256 / CG;
    constexpr int R4  = RB / RPP;
    constexpr int K4T = KT / 4;
    __shared__ float4 wlds[KT * CG];
    __shared__ float4 xlds[RB * K4T];

    int bid = blockIdx.x, g = bid / 5, r = bid - g * 5;
    if (r >= 3) {
        // histogram role (2 of every 5 blocks)
        int i = (g * 2 + (r - 3)) * 256 + (int)threadIdx.x;
        for (; i < E; i += HTH) {
            atomicAdd(&degO[src[i]], 1);
            atomicAdd(&degI[dst[i]], 1);
        }
        return;
    }
    int pidx = g * 3 + r;
    if (pidx >= PB) return;
    int n0 = pidx * RB;
    proj_body<DIN, DOUT, RB, KT>(x, W, N, n0, wlds, xlds,
        [&](float4 (&acc)[R4], int rp, int cg) {
#pragma unroll
            for (int rr = 0; rr < R4; ++rr) {
                int n = n0 + rp + rr * RPP;
                if (n < N) {
                    ushort4 s;
                    s.x = f2bf(acc[rr].x); s.y = f2bf(acc[rr].y);
                    s.z = f2bf(acc[rr].z); s.w = f2bf(acc[rr].w);
                    *(ushort4*)(outbf + (size_t)n * DOUT + cg * 4) = s;
                }
            }
        });
}

// ---------------- proj (fp32 out, *nrm[n]) -----------------------------------
template<int DIN, int DOUT, int RB, int KT>
__global__ void __launch_bounds__(256) k_proj_gl2(
        const float* __restrict__ in, const float* __restrict__ nrm,
        const float* __restrict__ W, float* __restrict__ out, int N) {
    constexpr int CG  = DOUT / 4;
    constexpr int RPP = 256 / CG;
    constexpr int R4  = RB / RPP;
    constexpr int K4T = KT / 4;
    __shared__ float4 wlds[KT * CG];
    __shared__ float4 xlds[RB * K4T];
    int n0 = blockIdx.x * RB;
    proj_body<DIN, DOUT, RB, KT>(in, W, N, n0, wlds, xlds,
        [&](float4 (&acc)[R4], int rp, int cg) {
#pragma unroll
            for (int rr = 0; rr < R4; ++rr) {
                int n = n0 + rp + rr * RPP;
                if (n < N) {
                    float nm = nrm[n];
                    float4 o = make_float4(acc[rr].x * nm, acc[rr].y * nm,
                                           acc[rr].z * nm, acc[rr].w * nm);
                    *(float4*)(out + (size_t)n * DOUT + cg * 4) = o;
                }
            }
        });
}

// ---------------- small proj (global-x), EPI 0: *nrm; 1: *nrm+bias -----------
template<int DIN, int DOUT, int R4, int KT, int EPI>
__global__ void __launch_bounds__(256) k_proj_lds(
        const float* __restrict__ in, const float* __restrict__ nrm,
        const float* __restrict__ W, const float* __restrict__ bias,
        float* __restrict__ out, int N) {
    constexpr int CG  = DOUT / 4;
    constexpr int RPP = 256 / CG;
    constexpr int RB  = RPP * R4;
    constexpr int NKT = DIN / KT;
    __shared__ float4 wlds[KT * CG];

    int tid = threadIdx.x;
    int rp  = tid / CG;
    int cg  = tid - rp * CG;
    bool active = (rp < RPP);
    int n0 = blockIdx.x * RB;

    int nrow[R4];
    const float4* xr[R4];
#pragma unroll
    for (int r = 0; r < R4; ++r) {
        int n = n0 + rp + r * RPP;
        nrow[r] = n;
        int nc = n < N ? n : N - 1;
        xr[r] = (const float4*)(in + (size_t)nc * DIN);
    }
    float4 acc[R4];
#pragma unroll
    for (int r = 0; r < R4; ++r) acc[r] = make_float4(0.f, 0.f, 0.f, 0.f);

    for (int kt = 0; kt < NKT; ++kt) {
        const float4* wsrc = (const float4*)(W + (size_t)kt * KT * DOUT);
        for (int i = tid; i < KT * CG; i += 256) wlds[i] = wsrc[i];
        __syncthreads();
        if (active) {
#pragma unroll 2
            for (int k4 = 0; k4 < KT / 4; ++k4) {
                float4 w0 = wlds[(k4 * 4 + 0) * CG + cg];
                float4 w1 = wlds[(k4 * 4 + 1) * CG + cg];
                float4 w2 = wlds[(k4 * 4 + 2) * CG + cg];
                float4 w3 = wlds[(k4 * 4 + 3) * CG + cg];
#pragma unroll
                for (int r = 0; r < R4; ++r) {
                    float4 xv = xr[r][kt * (KT / 4) + k4];
                    acc[r].x = fmaf(xv.x, w0.x, acc[r].x);
                    acc[r].y = fmaf(xv.x, w0.y, acc[r].y);
                    acc[r].z = fmaf(xv.x, w0.z, acc[r].z);
                    acc[r].w = fmaf(xv.x, w0.w, acc[r].w);
                    acc[r].x = fmaf(xv.y, w1.x, acc[r].x);
                    acc[r].y = fmaf(xv.y, w1.y, acc[r].y);
                    acc[r].z = fmaf(xv.y, w1.z, acc[r].z);
                    acc[r].w = fmaf(xv.y, w1.w, acc[r].w);
                    acc[r].x = fmaf(xv.z, w2.x, acc[r].x);
                    acc[r].y = fmaf(xv.z, w2.y, acc[r].y);
                    acc[r].z = fmaf(xv.z, w2.z, acc[r].z);
                    acc[r].w = fmaf(xv.z, w2.w, acc[r].w);
                    acc[r].x = fmaf(xv.w, w3.x, acc[r].x);
                    acc[r].y = fmaf(xv.w, w3.y, acc[r].y);
                    acc[r].z = fmaf(xv.w, w3.z, acc[r].z);
                    acc[r].w = fmaf(xv.w, w3.w, acc[r].w);
                }
            }
        }
        __syncthreads();
    }
    if (active) {
#pragma unroll
        for (int r = 0; r < R4; ++r) {
            int n = nrow[r];
            if (n < N) {
                float nm = nrm[n];
                float4 o;
                if (EPI == 0) {
                    o = make_float4(acc[r].x * nm, acc[r].y * nm,
                                    acc[r].z * nm, acc[r].w * nm);
                } else {
                    float4 b = *(const float4*)(bias + cg * 4);
                    o.x = fmaf(acc[r].x, nm, b.x);
                    o.y = fmaf(acc[r].y, nm, b.y);
                    o.z = fmaf(acc[r].z, nm, b.z);
                    o.w = fmaf(acc[r].w, nm, b.w);
                }
                *(float4*)(out + (size_t)n * DOUT + cg * 4) = o;
            }
        }
    }
}

// ---------------- norms ----------------
__global__ void k_prep(const int* __restrict__ degO, const int* __restrict__ degI,
                       float* __restrict__ nSf, float* __restrict__ nDf, int N) {
    int i = blockIdx.x * 256 + threadIdx.x;
    if (i < N) {
        int a = degO[i]; nSf[i] = rsqrtf((float)(a > 1 ? a : 1));
        int b = degI[i]; nDf[i] = rsqrtf((float)(b > 1 ? b : 1));
    }
}

// ---------------- prefix scan (1024 elems / block) ----------------
__global__ void k_blocksum(const int* __restrict__ deg, int* __restrict__ bsum, int N) {
    __shared__ int sh[256];
    int base = blockIdx.x * 1024;
    int s = 0;
    for (int i = threadIdx.x; i < 1024; i += 256) {
        int idx = base + i;
        s += (idx < N) ? deg[idx] : 0;
    }
    sh[threadIdx.x] = s; __syncthreads();
    for (int off = 128; off > 0; off >>= 1) {
        if (threadIdx.x < off) sh[threadIdx.x] += sh[threadIdx.x + off];
        __syncthreads();
    }
    if (threadIdx.x == 0) bsum[blockIdx.x] = sh[0];
}

__global__ void k_scan_bsums(const int* __restrict__ bsum, int* __restrict__ boffs, int nb) {
    if (blockIdx.x == 0 && threadIdx.x == 0) {
        int run = 0;
        for (int i = 0; i < nb; ++i) { boffs[i] = run; run += bsum[i]; }
    }
}

// dual-store: rowptr[idx] AND cursor[idx] (replaces the D2D memcpy node,
// which is the round-6 replay-divergence suspect: SDMA copy in graph).
__global__ void k_blockscan(const int* __restrict__ deg, const int* __restrict__ boffs,
                            int* __restrict__ rowptr, int* __restrict__ cursor, int N) {
    __shared__ int sh[256];
    int base = blockIdx.x * 1024;
    int i0 = base + threadIdx.x * 4;
    int v[4]; int tot = 0;
#pragma unroll
    for (int r = 0; r < 4; ++r) {
        int idx = i0 + r;
        v[r] = (idx < N) ? deg[idx] : 0;
        tot += v[r];
    }
    sh[threadIdx.x] = tot; __syncthreads();
    for (int off = 1; off < 256; off <<= 1) {
        int t = (threadIdx.x >= off) ? sh[threadIdx.x - off] : 0;
        __syncthreads();
        sh[threadIdx.x] += t;
        __syncthreads();
    }
    int run = sh[threadIdx.x] - tot + boffs[blockIdx.x];
#pragma unroll
    for (int r = 0; r < 4; ++r) {
        int idx = i0 + r;
        if (idx < N) { rowptr[idx] = run; cursor[idx] = run; }
        run += v[r];
    }
}

__global__ void k_fill2(const int* __restrict__ src, const int* __restrict__ dst,
                        int* __restrict__ cursor, int* __restrict__ col, int E) {
    int stride = gridDim.x * blockDim.x;
    for (int i = blockIdx.x * blockDim.x + threadIdx.x; i < E; i += stride) {
        int pos = atomicAdd(&cursor[dst[i]], 1);
        col[pos] = src[i];
    }
}

// ---------------- bf16 gather with per-edge nS (layer 1) ----------------
template<int DOUT>
__global__ void __launch_bounds__(256) k_gather_b(
        const int* __restrict__ rowptr, const int* __restrict__ col,
        const int* __restrict__ degI, const float* __restrict__ nSf,
        const float* __restrict__ nDf, const ushort_t* __restrict__ projbf,
        const float* __restrict__ bias, float* __restrict__ out, int N) {
    constexpr int CGB = DOUT / 8;
    long t = blockIdx.x * 256L + threadIdx.x;
    if (t >= (long)N * CGB) return;
    int n  = (int)(t / CGB);
    int cb = (int)(t - (long)n * CGB);
    int beg = rowptr[n];
    int dg  = degI[n];
    float acc[8];
#pragma unroll
    for (int k = 0; k < 8; ++k) acc[k] = 0.f;
    int i = 0;
    for (; i + 2 <= dg; i += 2) {
        int s0 = col[beg + i];
        int s1 = col[beg + i + 1];
        float ns0 = nSf[s0];
        float ns1 = nSf[s1];
        uint4 v0 = *(const uint4*)(projbf + (size_t)s0 * DOUT + cb * 8);
        uint4 v1 = *(const uint4*)(projbf + (size_t)s1 * DOUT + cb * 8);
        acc[0] = fmaf(ns0, BFLO(v0.x), acc[0]);
        acc[1] = fmaf(ns0, BFHI(v0.x), acc[1]);
        acc[2] = fmaf(ns0, BFLO(v0.y), acc[2]);
        acc[3] = fmaf(ns0, BFHI(v0.y), acc[3]);
        acc[4] = fmaf(ns0, BFLO(v0.z), acc[4]);
        acc[5] = fmaf(ns0, BFHI(v0.z), acc[5]);
        acc[6] = fmaf(ns0, BFLO(v0.w), acc[6]);
        acc[7] = fmaf(ns0, BFHI(v0.w), acc[7]);
        acc[0] = fmaf(ns1, BFLO(v1.x), acc[0]);
        acc[1] = fmaf(ns1, BFHI(v1.x), acc[1]);
        acc[2] = fmaf(ns1, BFLO(v1.y), acc[2]);
        acc[3] = fmaf(ns1, BFHI(v1.y), acc[3]);
        acc[4] = fmaf(ns1, BFLO(v1.z), acc[4]);
        acc[5] = fmaf(ns1, BFHI(v1.z), acc[5]);
        acc[6] = fmaf(ns1, BFLO(v1.w), acc[6]);
        acc[7] = fmaf(ns1, BFHI(v1.w), acc[7]);
    }
    if (i < dg) {
        int s0 = col[beg + i];
        float ns0 = nSf[s0];
        uint4 v0 = *(const uint4*)(projbf + (size_t)s0 * DOUT + cb * 8);
        acc[0] = fmaf(ns0, BFLO(v0.x), acc[0]);
        acc[1] = fmaf(ns0, BFHI(v0.x), acc[1]);
        acc[2] = fmaf(ns0, BFLO(v0.y), acc[2]);
        acc[3] = fmaf(ns0, BFHI(v0.y), acc[3]);
        acc[4] = fmaf(ns0, BFLO(v0.z), acc[4]);
        acc[5] = fmaf(ns0, BFHI(v0.z), acc[5]);
        acc[6] = fmaf(ns0, BFLO(v0.w), acc[6]);
        acc[7] = fmaf(ns0, BFHI(v0.w), acc[7]);
    }
    float nm = nDf[n];
    float o[8];
#pragma unroll
    for (int k = 0; k < 8; ++k) {
        o[k] = fmaf(acc[k], nm, bias[cb * 8 + k]);
        o[k] = fmaxf(o[k], 0.f);
    }
    float* dstp = out + (size_t)n * DOUT + cb * 8;
    *(float4*)(dstp)     = make_float4(o[0], o[1], o[2], o[3]);
    *(float4*)(dstp + 4) = make_float4(o[4], o[5], o[6], o[7]);
}

// ---------------- fp32 CSR gather + fused epilogue ----------------
template<int DOUT, bool RELU, bool NORMBIAS, bool SCALESRC>
__global__ void __launch_bounds__(256) k_gather(
        const int* __restrict__ rowptr, const int* __restrict__ col,
        const int* __restrict__ degI, const float* __restrict__ nSf,
        const float* __restrict__ nDf, const float* __restrict__ proj,
        const float* __restrict__ bias, float* __restrict__ out, int N) {
    constexpr int CG = DOUT / 4;
    long t = blockIdx.x * 256L + threadIdx.x;
    if (t >= (long)N * CG) return;
    int n  = (int)(t / CG);
    int cg = (int)(t - (long)n * CG);
    int beg = rowptr[n];
    int dg  = degI[n];
    float4 a0 = make_float4(0.f, 0.f, 0.f, 0.f);
    float4 a1 = make_float4(0.f, 0.f, 0.f, 0.f);
    float4 a2 = make_float4(0.f, 0.f, 0.f, 0.f);
    float4 a3 = make_float4(0.f, 0.f, 0.f, 0.f);
    int i = 0;
    for (; i + 4 <= dg; i += 4) {
        int s0 = col[beg + i];
        int s1 = col[beg + i + 1];
        int s2 = col[beg + i + 2];
        int s3 = col[beg + i + 3];
        float4 v0 = *(const float4*)(proj + (size_t)s0 * DOUT + cg * 4);
        float4 v1 = *(const float4*)(proj + (size_t)s1 * DOUT + cg * 4);
        float4 v2 = *(const float4*)(proj + (size_t)s2 * DOUT + cg * 4);
        float4 v3 = *(const float4*)(proj + (size_t)s3 * DOUT + cg * 4);
        a0.x += v0.x; a0.y += v0.y; a0.z += v0.z; a0.w += v0.w;
        a1.x += v1.x; a1.y += v1.y; a1.z += v1.z; a1.w += v1.w;
        a2.x += v2.x; a2.y += v2.y; a2.z += v2.z; a2.w += v2.w;
        a3.x += v3.x; a3.y += v3.y; a3.z += v3.z; a3.w += v3.w;
    }
    for (; i < dg; ++i) {
        int s0 = col[beg + i];
        float4 v0 = *(const float4*)(proj + (size_t)s0 * DOUT + cg * 4);
        a0.x += v0.x; a0.y += v0.y; a0.z += v0.z; a0.w += v0.w;
    }
    float4 o = make_float4(a0.x + a1.x + a2.x + a3.x,
                           a0.y + a1.y + a2.y + a3.y,
                           a0.z + a1.z + a2.z + a3.z,
                           a0.w + a1.w + a2.w + a3.w);
    if (NORMBIAS) {
        float nm = nDf[n];
        float4 b = *(const float4*)(bias + cg * 4);
        o.x = fmaf(o.x, nm, b.x);
        o.y = fmaf(o.y, nm, b.y);
        o.z = fmaf(o.z, nm, b.z);
        o.w = fmaf(o.w, nm, b.w);
    }
    if (RELU) {
        o.x = fmaxf(o.x, 0.f); o.y = fmaxf(o.y, 0.f);
        o.z = fmaxf(o.z, 0.f); o.w = fmaxf(o.w, 0.f);
    }
    if (SCALESRC) {
        float ns = nSf[n];
        o.x *= ns; o.y *= ns; o.z *= ns; o.w *= ns;
    }
    *(float4*)(out + (size_t)n * DOUT + cg * 4) = o;
}

static inline int cdiv(long a, int b) { return (int)((a + b - 1) / b); }

extern "C" void kernel_launch(void* const* d_in, const int* in_sizes, int n_in,
                              void* d_out, int out_size, void* d_ws, size_t ws_size,
                              hipStream_t stream) {
    const float* x   = (const float*)d_in[0];
    const int*   src = (const int*)d_in[1];
    const int*   dst = (const int*)d_in[2];
    const float* W1 = (const float*)d_in[3];  const float* b1 = (const float*)d_in[4];
    const float* W2 = (const float*)d_in[5];  const float* b2 = (const float*)d_in[6];
    const float* W3 = (const float*)d_in[7];  const float* b3 = (const float*)d_in[8];
    const float* W4 = (const float*)d_in[9];  const float* b4 = (const float*)d_in[10];

    const int N = in_sizes[0] / 256;
    const int E = in_sizes[1];

    // ---- workspace layout ----
    int* ws_i = (int*)d_ws;
    int* degO   = ws_i;                       // [N]
    int* degI   = ws_i + N;                   // [N]
    int* rowptr = ws_i + 2 * (size_t)N;       // [N]
    int* col    = ws_i + 3 * (size_t)N;       // [E]
    float* nSf  = (float*)(ws_i + 3 * (size_t)N + E);  // [N]
    float* nDf  = nSf + N;                    // [N]
    float* projb = nDf + N;                   // N*64 f32 (== N*128 bf16)
    float* hbuf  = projb + (size_t)N * 64;    // N*128 f32
    ushort_t* projbf = (ushort_t*)projb;
    // CSR-build scratch aliased into hbuf (dead before first hbuf write)
    int* bsum   = (int*)hbuf;                 // [<=4096]
    int* boffs  = bsum + 4096;                // [<=4096]
    int* cursor = bsum + 16384;               // [N]

    int nb = (N + 1023) / 1024;
    int PB = cdiv(N, 64);
    int G5 = cdiv(PB, 3);
    int HTH = (2 * G5) * 256;

    // ---- combined: histogram || proj1 (bf16, un-normalized) ----
    hipMemsetAsync(degO, 0, 2 * (size_t)N * sizeof(int), stream);
    k_comb<256, 128, 64, 32><<<5 * G5, 256, 0, stream>>>(
        x, W1, projbf, N, src, dst, degO, degI, E, PB, HTH);

    // ---- norms + CSR (cursor dual-stored in k_blockscan; no memcpy node) ----
    k_prep<<<cdiv(N, 256), 256, 0, stream>>>(degO, degI, nSf, nDf, N);
    k_blocksum<<<nb, 256, 0, stream>>>(degI, bsum, N);
    k_scan_bsums<<<1, 64, 0, stream>>>(bsum, boffs, nb);
    k_blockscan<<<nb, 256, 0, stream>>>(degI, boffs, rowptr, cursor, N);
    k_fill2<<<2048, 256, 0, stream>>>(src, dst, cursor, col, E);

    // ---- layer 1 aggregate: bf16 gather w/ per-edge nS -> hbuf (h1) ----
    k_gather_b<128><<<cdiv((long)N * 16, 256), 256, 0, stream>>>(
        rowptr, col, degI, nSf, nDf, projbf, b1, hbuf, N);

    // ---- layer 2: proj (h1*nS)@W2 -> projb; gather -> hbuf (h2) ----
    k_proj_gl2<128, 64, 64, 32><<<cdiv(N, 64), 256, 0, stream>>>(
        hbuf, nSf, W2, projb, N);
    k_gather<64, true, true, false><<<cdiv((long)N * 16, 256), 256, 0, stream>>>(
        rowptr, col, degI, nSf, nDf, projb, b2, hbuf, N);

    // ---- layer 3: proj -> projb; gather (+relu+nD+b3, then *nS) -> hbuf (t4) ----
    k_proj_lds<64, 16, 1, 64, 0><<<cdiv(N, 64), 256, 0, stream>>>(
        hbuf, nSf, W3, nullptr, projb, N);
    k_gather<16, true, true, true><<<cdiv((long)N * 4, 256), 256, 0, stream>>>(
        rowptr, col, degI, nSf, nDf, projb, b3, hbuf, N);

    // ---- layer 4 (aggregate-first): gather t4 -> projb; (agg@W4)*nD+b4 -> out ----
    k_gather<16, false, false, false><<<cdiv((long)N * 4, 256), 256, 0, stream>>>(
        rowptr, col, degI, nSf, nDf, hbuf, nullptr, projb, N);
    k_proj_lds<16, 40, 2, 16, 1><<<cdiv(N, 50), 256, 0, stream>>>(
        projb, nDf, W4, b4, (float*)d_out, N);
}